// Round 13
// baseline (148.207 us; speedup 1.0000x reference)
//
#include <hip/hip_runtime.h>
#include <cmath>

#define B_ 4
#define S_ 2048
#define E_ 768
#define H_ 12
#define D_ 64
#define NE3 (3*E_)          // 2304
#define QKV_ELEMS ((size_t)B_*H_*S_*D_)   // 6,291,456 per tensor
#define BHS ((size_t)B_*H_*S_)            // 98,304

typedef __attribute__((ext_vector_type(8)))  short bf16x8;   // 8 bf16 = 4 VGPR
typedef __attribute__((ext_vector_type(4)))  float f32x4;
typedef __attribute__((ext_vector_type(16))) float f32x16;

__device__ __forceinline__ unsigned short f2bf(float f) {
    union { float f; unsigned u; } v; v.f = f;
    return (unsigned short)((v.u + 0x7FFFu + ((v.u >> 16) & 1u)) >> 16);  // RNE
}
__device__ __forceinline__ float bf2f(unsigned short u) {
    union { unsigned u; float f; } v; v.u = (unsigned)u << 16; return v.f;
}
__device__ __forceinline__ float exp2_fast(float x) {       // 2^x via v_exp_f32
    float r; asm("v_exp_f32 %0, %1" : "=v"(r) : "v"(x)); return r;
}
__device__ __forceinline__ float max3f(float a, float b, float c) {
    float r; asm("v_max3_f32 %0, %1, %2, %3" : "=v"(r) : "v"(a), "v"(b), "v"(c));
    return r;
}
#define LOG2E 1.44269504088896340736f

// ---------------------------------------------------------------------------
// Pre-pass 1: x fp32 -> bf16. (unchanged)
// ---------------------------------------------------------------------------
__global__ __launch_bounds__(256)
void cvt_x(const float* __restrict__ x, unsigned short* __restrict__ xb)
{
    const size_t i = ((size_t)blockIdx.x * 256 + threadIdx.x) * 8;
    float4 a = *(const float4*)(x + i);
    float4 b = *(const float4*)(x + i + 4);
    ushort4 o0, o1;
    o0.x = f2bf(a.x); o0.y = f2bf(a.y); o0.z = f2bf(a.z); o0.w = f2bf(a.w);
    o1.x = f2bf(b.x); o1.y = f2bf(b.y); o1.z = f2bf(b.z); o1.w = f2bf(b.w);
    *(ushort4*)(xb + i)     = o0;
    *(ushort4*)(xb + i + 4) = o1;
}

// ---------------------------------------------------------------------------
// Pre-pass 2: W [768][2304] fp32 -> Wt [2304][768] bf16 (transpose). (unchanged)
// ---------------------------------------------------------------------------
__global__ __launch_bounds__(256)
void transpose_w(const float* __restrict__ W, unsigned short* __restrict__ Wt)
{
    __shared__ float t[32][33];
    const int tx = threadIdx.x & 31;
    const int ty = threadIdx.x >> 5;
    const int n0 = blockIdx.x * 32;
    const int k0 = blockIdx.y * 32;
    #pragma unroll
    for (int r = 0; r < 4; ++r)
        t[ty + 8*r][tx] = W[(size_t)(k0 + ty + 8*r) * NE3 + n0 + tx];
    __syncthreads();
    #pragma unroll
    for (int r = 0; r < 4; ++r)
        Wt[(size_t)(n0 + ty + 8*r) * E_ + k0 + tx] = f2bf(t[tx][ty + 8*r]);
}

// ---------------------------------------------------------------------------
// QKV GEMM, bf16 MFMA. (unchanged from round 11/12: V written transposed
// [B,H,D,S] into vtg; Q pre-scaled by 0.125; V slot of qkv never written)
// ---------------------------------------------------------------------------
__global__ __launch_bounds__(256, 2)
void qkv_gemm_mfma(const unsigned short* __restrict__ xb,
                   const unsigned short* __restrict__ Wt,
                   const float* __restrict__ bias,
                   unsigned short* __restrict__ qkv,
                   unsigned short* __restrict__ vtg)
{
    __shared__ __align__(16) unsigned short As[128*64];
    __shared__ __align__(16) unsigned short Bs[128*64];

    const int tid  = threadIdx.x;
    const int lane = tid & 63;
    const int wave = tid >> 6;
    const int lo   = lane & 15;
    const int hi   = lane >> 4;
    const int wr   = wave >> 1;
    const int wc   = wave & 1;
    const int nstart = blockIdx.x * 128;
    const int mstart = blockIdx.y * 128;

    f32x4 acc[4][4];
    #pragma unroll
    for (int i = 0; i < 4; ++i)
        #pragma unroll
        for (int j = 0; j < 4; ++j) acc[i][j] = (f32x4){0.f,0.f,0.f,0.f};

    for (int k0 = 0; k0 < E_; k0 += 64) {
        __syncthreads();
        #pragma unroll
        for (int it = 0; it < 4; ++it) {
            const int cid = tid + it*256;
            const int row = cid >> 3, c = cid & 7;
            bf16x8 av = *(const bf16x8*)(xb + (size_t)(mstart + row)*E_ + k0 + c*8);
            *(bf16x8*)&As[row*64 + ((c ^ (row & 7)) * 8)] = av;
            bf16x8 bv = *(const bf16x8*)(Wt + (size_t)(nstart + row)*E_ + k0 + c*8);
            *(bf16x8*)&Bs[row*64 + ((c ^ (row & 7)) * 8)] = bv;
        }
        __syncthreads();

        #pragma unroll
        for (int ks = 0; ks < 2; ++ks) {
            const int c = ks*4 + hi;
            bf16x8 af[4], bfr[4];
            #pragma unroll
            for (int i = 0; i < 4; ++i) {
                const int ar = wr*64 + i*16 + lo;
                af[i] = *(const bf16x8*)&As[ar*64 + ((c ^ (ar & 7)) * 8)];
            }
            #pragma unroll
            for (int j = 0; j < 4; ++j) {
                const int br = wc*64 + j*16 + lo;
                bfr[j] = *(const bf16x8*)&Bs[br*64 + ((c ^ (br & 7)) * 8)];
            }
            #pragma unroll
            for (int i = 0; i < 4; ++i)
                #pragma unroll
                for (int j = 0; j < 4; ++j)
                    acc[i][j] = __builtin_amdgcn_mfma_f32_16x16x32_bf16(
                        af[i], bfr[j], acc[i][j], 0, 0, 0);
        }
    }

    #pragma unroll
    for (int j = 0; j < 4; ++j) {
        const int ncol = nstart + wc*64 + j*16 + lo;
        const int g  = ncol >> 6;
        const int cq = g / H_;         // 0:Q 1:K 2:V
        const int h  = g % H_;
        const int d  = ncol & 63;
        const float bv = bias[ncol];
        const float qscale = (cq == 0) ? 0.125f : 1.0f;   // fold in 1/sqrt(D)
        unsigned short* dst = qkv + (size_t)cq * QKV_ELEMS;
        #pragma unroll
        for (int i = 0; i < 4; ++i) {
            const int mbase = mstart + wr*64 + i*16 + hi*4;
            const int b  = mbase >> 11;
            const int s0 = mbase & 2047;     // 4-aligned; +3 can't cross 2048
            if (cq == 2) {
                ushort4 vv;
                vv.x = f2bf(acc[i][j][0] + bv);
                vv.y = f2bf(acc[i][j][1] + bv);
                vv.z = f2bf(acc[i][j][2] + bv);
                vv.w = f2bf(acc[i][j][3] + bv);
                *(ushort4*)(vtg + (((size_t)(b*H_ + h))*D_ + d)*S_ + s0) = vv;
            } else {
                #pragma unroll
                for (int r = 0; r < 4; ++r)
                    dst[(((size_t)(b*H_ + h))*S_ + s0 + r)*D_ + d] =
                        f2bf((acc[i][j][r] + bv) * qscale);
            }
        }
    }
}

// ---------------------------------------------------------------------------
// Flash attention, 32x32x16 bf16 MFMA, swapped operands. Round-13 change:
// K-SPLIT x2 (flash-decoding): blockIdx.z selects keys [z*1024, z*1024+1024).
// Grid doubles (1536 blocks -> 5 blocks/CU at 32KB LDS, waves/SIMD 3->5).
// Body = round-11 validated double-buffer kernel; epilogue writes normalized
// partial O (bf16) + (m,l) f32; combine_out merges the two splits.
// ---------------------------------------------------------------------------
__global__ __launch_bounds__(256, 2)
void attn_mfma32(const unsigned short* __restrict__ qkv,
                 const unsigned short* __restrict__ vtg,
                 unsigned short* __restrict__ po0,
                 unsigned short* __restrict__ po1,
                 float* __restrict__ ml)
{
    __shared__ __align__(16) unsigned short Ks[2*64*64];  // [buf][key][d], swizzled
    __shared__ __align__(16) unsigned short Vt[2*64*64];  // [buf][d][key], swizzled

    const int tid  = threadIdx.x;
    const int lane = tid & 63;
    const int wave = tid >> 6;       // 0..3
    const int q32  = lane & 31;
    const int hi   = lane >> 5;      // 0..1
    const int qtile = blockIdx.x * 128;
    const int bh = blockIdx.y;
    const int split = blockIdx.z;    // 0,1
    const int kbase = split * (S_/2);
    const size_t base  = (size_t)bh * S_ * D_;
    const size_t baseT = (size_t)bh * D_ * S_;

    const unsigned short* Q = qkv;
    const unsigned short* K = qkv + QKV_ELEMS;

    // Q as B-operand: col=q32, k-elems d = m*16 + hi*8 + j
    bf16x8 qf[4];
    {
        const size_t qrow = base + (size_t)(qtile + wave*32 + q32) * D_;
        #pragma unroll
        for (int m = 0; m < 4; ++m)
            qf[m] = *(const bf16x8*)(Q + qrow + m*16 + hi*8);
    }

    // K staging ids: LDS pos (key=cid>>3, slot=cid&7); source d-chunk = slot^(key&7)
    const int kkey0 = tid >> 3,          kch0 = tid & 7;
    const int kkey1 = (tid + 256) >> 3,  kch1 = (tid + 256) & 7;
    // V^T staging ids: LDS pos (d=cid>>3, slot=cid&7); source key-chunk = slot^(d&7)
    const int vd0 = tid >> 3, vs0 = tid & 7;
    const int vd1 = vd0 + 32;                 // (vd1&7)==(vd0&7)

    #define GLOADK(kc_, buf_) do {                                                   \
        __builtin_amdgcn_global_load_lds(                                            \
            (const __attribute__((address_space(1))) unsigned*)                      \
                (K + base + (size_t)((kc_) + kkey0)*D_ + ((kch0 ^ (kkey0 & 7))*8)),  \
            (__attribute__((address_space(3))) unsigned*)&Ks[(buf_)*4096 + tid*8],   \
            16, 0, 0);                                                               \
        __builtin_amdgcn_global_load_lds(                                            \
            (const __attribute__((address_space(1))) unsigned*)                      \
                (K + base + (size_t)((kc_) + kkey1)*D_ + ((kch1 ^ (kkey1 & 7))*8)),  \
            (__attribute__((address_space(3))) unsigned*)&Ks[(buf_)*4096 + (tid+256)*8], \
            16, 0, 0);                                                               \
    } while (0)
    #define GLOADV(kc_, buf_) do {                                                   \
        __builtin_amdgcn_global_load_lds(                                            \
            (const __attribute__((address_space(1))) unsigned*)                      \
                (vtg + baseT + (size_t)vd0*S_ + (kc_) + ((vs0 ^ (vd0 & 7))*8)),      \
            (__attribute__((address_space(3))) unsigned*)&Vt[(buf_)*4096 + tid*8],   \
            16, 0, 0);                                                               \
        __builtin_amdgcn_global_load_lds(                                            \
            (const __attribute__((address_space(1))) unsigned*)                      \
                (vtg + baseT + (size_t)vd1*S_ + (kc_) + ((vs0 ^ (vd1 & 7))*8)),      \
            (__attribute__((address_space(3))) unsigned*)&Vt[(buf_)*4096 + (tid+256)*8], \
            16, 0, 0);                                                               \
    } while (0)

    f32x16 o0, o1;       // O^T accum: u=0 -> d=0..31, u=1 -> d=32..63 (col=q32)
    #pragma unroll
    for (int r = 0; r < 16; ++r) { o0[r] = 0.f; o1[r] = 0.f; }
    float m_run = -INFINITY, l_run = 0.f;

    // prologue: stage this split's chunk 0
    GLOADK(kbase, 0);
    GLOADV(kbase, 0);
    __syncthreads();
    int cur = 0;

    for (int kc = kbase; kc < kbase + S_/2; kc += 64) {
        // issue next chunk's DMA now; buf[cur^1] is free (barrier passed)
        int nkc = kc + 64; if (nkc >= kbase + S_/2) nkc -= S_/2;
        GLOADK(nkc, cur ^ 1);
        GLOADV(nkc, cur ^ 1);

        const int o = cur * 4096;

        // ---- S^T = K · Q^T : sg[g] covers keys [kc+32g, kc+32g+32)
        f32x16 sg[2];
        __builtin_amdgcn_s_setprio(1);
        #pragma unroll
        for (int g = 0; g < 2; ++g) {
            f32x16 acc;
            #pragma unroll
            for (int r = 0; r < 16; ++r) acc[r] = 0.f;
            const int key = g*32 + q32;
            #pragma unroll
            for (int m = 0; m < 4; ++m) {
                const int c = m*2 + hi;
                bf16x8 kf = *(const bf16x8*)&Ks[o + key*64 + ((c ^ (key & 7)) * 8)];
                acc = __builtin_amdgcn_mfma_f32_32x32x16_bf16(kf, qf[m], acc, 0, 0, 0);
            }
            sg[g] = acc;
        }
        __builtin_amdgcn_s_setprio(0);

        // ---- online softmax, per-lane q = q32; partner = lane^32
        float m0 = fmaxf(sg[0][0], sg[0][1]);
        float m1 = fmaxf(sg[0][8], sg[0][9]);
        float m2 = fmaxf(sg[1][0], sg[1][1]);
        float m3 = fmaxf(sg[1][8], sg[1][9]);
        #pragma unroll
        for (int r = 2; r < 8; r += 2) {
            m0 = max3f(m0, sg[0][r],   sg[0][r+1]);
            m1 = max3f(m1, sg[0][r+8], sg[0][r+9]);
            m2 = max3f(m2, sg[1][r],   sg[1][r+1]);
            m3 = max3f(m3, sg[1][r+8], sg[1][r+9]);
        }
        float mx = fmaxf(fmaxf(m0, m1), fmaxf(m2, m3));
        mx = fmaxf(mx, __shfl_xor(mx, 32));      // validated cross-half max

        // defer-max (T13): only rescale when the max actually grew
        if (__any(mx > m_run + 8.0f)) {
            const float mn    = fmaxf(m_run, mx);
            const float alpha = exp2_fast((m_run - mn) * LOG2E);
            m_run = mn;
            l_run *= alpha;
            #pragma unroll
            for (int r = 0; r < 16; ++r) { o0[r] *= alpha; o1[r] *= alpha; }
        }
        const float nmnL = -m_run * LOG2E;

        // exp via 2^(s*log2e - m*log2e), in place
        #pragma unroll
        for (int r = 0; r < 16; ++r) sg[0][r] = exp2_fast(fmaf(sg[0][r], LOG2E, nmnL));
        #pragma unroll
        for (int r = 0; r < 16; ++r) sg[1][r] = exp2_fast(fmaf(sg[1][r], LOG2E, nmnL));

        // pairwise psum tree + validated cross-half add
        float a8[8];
        #pragma unroll
        for (int r = 0; r < 8; ++r) a8[r] = (sg[0][r] + sg[0][r+8]) + (sg[1][r] + sg[1][r+8]);
        float a4_0 = a8[0] + a8[4], a4_1 = a8[1] + a8[5];
        float a4_2 = a8[2] + a8[6], a4_3 = a8[3] + a8[7];
        float psum = (a4_0 + a4_1) + (a4_2 + a4_3);
        psum += __shfl_xor(psum, 32);
        l_run += psum;

        // ---- pack P to bf16 pairs: U[g][c] = pk(p[2c], p[2c+1])
        unsigned U0[8], U1[8];
        #pragma unroll
        for (int c2 = 0; c2 < 8; ++c2) {
            asm("v_cvt_pk_bf16_f32 %0, %1, %2"
                : "=v"(U0[c2]) : "v"(sg[0][2*c2]), "v"(sg[0][2*c2+1]));
            asm("v_cvt_pk_bf16_f32 %0, %1, %2"
                : "=v"(U1[c2]) : "v"(sg[1][2*c2]), "v"(sg[1][2*c2+1]));
        }

        // ---- exchange with partner (lane^32) — validated round-6/7 form
        unsigned R0[2][2], R1[2][2];
        #pragma unroll
        for (int tb = 0; tb < 2; ++tb)
            #pragma unroll
            for (int w2 = 0; w2 < 2; ++w2) {
                unsigned s0 = hi ? U0[4*tb + w2] : U0[4*tb + 2 + w2];
                unsigned s1 = hi ? U1[4*tb + w2] : U1[4*tb + 2 + w2];
                R0[tb][w2] = (unsigned)__shfl_xor((int)s0, 32);
                R1[tb][w2] = (unsigned)__shfl_xor((int)s1, 32);
            }

        // ---- PV: O^T += V^T · P^T  (validated mux)
        __builtin_amdgcn_s_setprio(1);
        #pragma unroll
        for (int t = 0; t < 4; ++t) {
            const int tb = t & 1;
            union { unsigned w[4]; bf16x8 v; } pw;
            if (t < 2) {
                pw.w[0] = hi ? R0[tb][0] : U0[4*tb + 0];
                pw.w[1] = hi ? R0[tb][1] : U0[4*tb + 1];
                pw.w[2] = hi ? U0[4*tb + 2] : R0[tb][0];
                pw.w[3] = hi ? U0[4*tb + 3] : R0[tb][1];
            } else {
                pw.w[0] = hi ? R1[tb][0] : U1[4*tb + 0];
                pw.w[1] = hi ? R1[tb][1] : U1[4*tb + 1];
                pw.w[2] = hi ? U1[4*tb + 2] : R1[tb][0];
                pw.w[3] = hi ? U1[4*tb + 3] : R1[tb][1];
            }
            const int c = t*2 + hi;
            {
                const int d = q32;
                bf16x8 vf = *(const bf16x8*)&Vt[o + d*64 + ((c ^ (d & 7)) * 8)];
                o0 = __builtin_amdgcn_mfma_f32_32x32x16_bf16(vf, pw.v, o0, 0, 0, 0);
            }
            {
                const int d = 32 + q32;
                bf16x8 vf = *(const bf16x8*)&Vt[o + d*64 + ((c ^ (d & 7)) * 8)];
                o1 = __builtin_amdgcn_mfma_f32_32x32x16_bf16(vf, pw.v, o1, 0, 0, 0);
            }
        }
        __builtin_amdgcn_s_setprio(0);

        __syncthreads();
        cur ^= 1;
    }

    // ---- epilogue: normalized partial O (bf16) + (m,l). Row q owned by lane
    // pair (q32, q32+32); d = 32u + 8rg + 4hi + i.
    const float inv = 1.f / l_run;
    const int qglob = qtile + wave*32 + q32;
    unsigned short* prow = (split ? po1 : po0) + ((size_t)bh*S_ + qglob)*64;
    #pragma unroll
    for (int rg = 0; rg < 4; ++rg) {
        ushort4 w0;
        w0.x = f2bf(o0[4*rg+0]*inv); w0.y = f2bf(o0[4*rg+1]*inv);
        w0.z = f2bf(o0[4*rg+2]*inv); w0.w = f2bf(o0[4*rg+3]*inv);
        *(ushort4*)(prow + rg*8 + hi*4) = w0;
        ushort4 w1;
        w1.x = f2bf(o1[4*rg+0]*inv); w1.y = f2bf(o1[4*rg+1]*inv);
        w1.z = f2bf(o1[4*rg+2]*inv); w1.w = f2bf(o1[4*rg+3]*inv);
        *(ushort4*)(prow + 32 + rg*8 + hi*4) = w1;
    }
    if (hi == 0) {
        float* mlp = ml + ((size_t)split*BHS + (size_t)bh*S_ + qglob)*2;
        mlp[0] = m_run;
        mlp[1] = l_run;
    }
    #undef GLOADK
    #undef GLOADV
}

// ---------------------------------------------------------------------------
// Combine the two K-split partials:
// out = (l0 e^{m0-M} O0 + l1 e^{m1-M} O1) / (l0 e^{m0-M} + l1 e^{m1-M})
// Grid (S/32, B*H), 256 thr; thread = (s_local = t>>3, d8 = (t&7)*8).
// ---------------------------------------------------------------------------
__global__ __launch_bounds__(256)
void combine_out(const unsigned short* __restrict__ po0,
                 const unsigned short* __restrict__ po1,
                 const float* __restrict__ ml,
                 float* __restrict__ out)
{
    const int tid = threadIdx.x;
    const int bh  = blockIdx.y;
    const int s   = blockIdx.x*32 + (tid >> 3);
    const int d8  = (tid & 7) * 8;
    const size_t row = (size_t)bh*S_ + s;

    const float mA = ml[row*2],         lA = ml[row*2 + 1];
    const float mB = ml[(BHS + row)*2], lB = ml[(BHS + row)*2 + 1];
    const float M  = fmaxf(mA, mB);
    float wA = lA * exp2_fast((mA - M) * LOG2E);
    float wB = lB * exp2_fast((mB - M) * LOG2E);
    const float inv = 1.f / (wA + wB);
    wA *= inv; wB *= inv;

    ushort4 a0 = *(const ushort4*)(po0 + row*64 + d8);
    ushort4 a1 = *(const ushort4*)(po0 + row*64 + d8 + 4);
    ushort4 b0 = *(const ushort4*)(po1 + row*64 + d8);
    ushort4 b1 = *(const ushort4*)(po1 + row*64 + d8 + 4);

    const int b = bh / H_;
    const int h = bh % H_;
    float* op = out + ((size_t)b*S_ + s)*E_ + h*64 + d8;
    float4 r0 = { wA*bf2f(a0.x) + wB*bf2f(b0.x), wA*bf2f(a0.y) + wB*bf2f(b0.y),
                  wA*bf2f(a0.z) + wB*bf2f(b0.z), wA*bf2f(a0.w) + wB*bf2f(b0.w) };
    float4 r1 = { wA*bf2f(a1.x) + wB*bf2f(b1.x), wA*bf2f(a1.y) + wB*bf2f(b1.y),
                  wA*bf2f(a1.z) + wB*bf2f(b1.z), wA*bf2f(a1.w) + wB*bf2f(b1.w) };
    *(float4*)op       = r0;
    *(float4*)(op + 4) = r1;
}

// ---------------------------------------------------------------------------
extern "C" void kernel_launch(void* const* d_in, const int* in_sizes, int n_in,
                              void* d_out, int out_size, void* d_ws, size_t ws_size,
                              hipStream_t stream)
{
    (void)in_sizes; (void)n_in; (void)out_size; (void)ws_size;
    const float* x    = (const float*)d_in[0];
    const float* W    = (const float*)d_in[1];
    const float* bias = (const float*)d_in[2];
    float* out = (float*)d_out;

    // Workspace (~68 MB), with safe aliasing (stream-ordered writes-after-reads):
    unsigned short* qkv = (unsigned short*)d_ws;       // Q,K slots; V slot unused
    unsigned short* po0 = qkv + 2*QKV_ELEMS;           // aliases unused V slot
    unsigned short* xb  = qkv + 3*QKV_ELEMS;           // read only by gemm
    unsigned short* po1 = xb;                          // attn writes AFTER gemm reads
    unsigned short* Wtb = xb + (size_t)B_*S_*E_;
    unsigned short* vtg = Wtb + (size_t)E_*NE3;        // V^T [B,H,D,S]
    float*          ml  = (float*)(vtg + QKV_ELEMS);   // 2*BHS*2 floats = 1.6 MB

    cvt_x<<<(B_*S_*E_)/(256*8), 256, 0, stream>>>(x, xb);
    transpose_w<<<dim3(NE3/32, E_/32), 256, 0, stream>>>(W, Wtb);

    dim3 g1(NE3/128, (B_*S_)/128);      // (18, 64)
    qkv_gemm_mfma<<<g1, 256, 0, stream>>>(xb, Wtb, bias, qkv, vtg);

    dim3 g2(S_/128, B_*H_, 2);          // (16, 48, 2) — K-split x2
    attn_mfma32<<<g2, 256, 0, stream>>>(qkv, vtg, po0, po1, ml);

    dim3 g3(S_/32, B_*H_);              // (64, 48)
    combine_out<<<g3, 256, 0, stream>>>(po0, po1, ml, out);
}

// Round 15
// 134.775 us; speedup vs baseline: 1.0997x; 1.0997x over previous
//
#include <hip/hip_runtime.h>
#include <cmath>

#define B_ 4
#define S_ 2048
#define E_ 768
#define H_ 12
#define D_ 64
#define NE3 (3*E_)          // 2304
#define QKV_ELEMS ((size_t)B_*H_*S_*D_)   // 6,291,456 per tensor

typedef __attribute__((ext_vector_type(8)))  short bf16x8;   // 8 bf16 = 4 VGPR
typedef __attribute__((ext_vector_type(4)))  float f32x4;
typedef __attribute__((ext_vector_type(16))) float f32x16;

__device__ __forceinline__ unsigned short f2bf(float f) {
    union { float f; unsigned u; } v; v.f = f;
    return (unsigned short)((v.u + 0x7FFFu + ((v.u >> 16) & 1u)) >> 16);  // RNE
}
__device__ __forceinline__ float exp2_fast(float x) {       // 2^x via v_exp_f32
    float r; asm("v_exp_f32 %0, %1" : "=v"(r) : "v"(x)); return r;
}
__device__ __forceinline__ float max3f(float a, float b, float c) {
    float r; asm("v_max3_f32 %0, %1, %2, %3" : "=v"(r) : "v"(a), "v"(b), "v"(c));
    return r;
}
#define LOG2E 1.44269504088896340736f

// ---------------------------------------------------------------------------
// Pre-pass 1: x fp32 -> bf16. (unchanged)
// ---------------------------------------------------------------------------
__global__ __launch_bounds__(256)
void cvt_x(const float* __restrict__ x, unsigned short* __restrict__ xb)
{
    const size_t i = ((size_t)blockIdx.x * 256 + threadIdx.x) * 8;
    float4 a = *(const float4*)(x + i);
    float4 b = *(const float4*)(x + i + 4);
    ushort4 o0, o1;
    o0.x = f2bf(a.x); o0.y = f2bf(a.y); o0.z = f2bf(a.z); o0.w = f2bf(a.w);
    o1.x = f2bf(b.x); o1.y = f2bf(b.y); o1.z = f2bf(b.z); o1.w = f2bf(b.w);
    *(ushort4*)(xb + i)     = o0;
    *(ushort4*)(xb + i + 4) = o1;
}

// ---------------------------------------------------------------------------
// Pre-pass 2: W [768][2304] fp32 -> Wt [2304][768] bf16 (transpose). (unchanged)
// ---------------------------------------------------------------------------
__global__ __launch_bounds__(256)
void transpose_w(const float* __restrict__ W, unsigned short* __restrict__ Wt)
{
    __shared__ float t[32][33];
    const int tx = threadIdx.x & 31;
    const int ty = threadIdx.x >> 5;
    const int n0 = blockIdx.x * 32;
    const int k0 = blockIdx.y * 32;
    #pragma unroll
    for (int r = 0; r < 4; ++r)
        t[ty + 8*r][tx] = W[(size_t)(k0 + ty + 8*r) * NE3 + n0 + tx];
    __syncthreads();
    #pragma unroll
    for (int r = 0; r < 4; ++r)
        Wt[(size_t)(n0 + ty + 8*r) * E_ + k0 + tx] = f2bf(t[tx][ty + 8*r]);
}

// ---------------------------------------------------------------------------
// QKV GEMM, bf16 MFMA. (unchanged from round 11: V written transposed
// [B,H,D,S] into vtg; Q pre-scaled by 0.125)
// ---------------------------------------------------------------------------
__global__ __launch_bounds__(256, 2)
void qkv_gemm_mfma(const unsigned short* __restrict__ xb,
                   const unsigned short* __restrict__ Wt,
                   const float* __restrict__ bias,
                   unsigned short* __restrict__ qkv,
                   unsigned short* __restrict__ vtg)
{
    __shared__ __align__(16) unsigned short As[128*64];
    __shared__ __align__(16) unsigned short Bs[128*64];

    const int tid  = threadIdx.x;
    const int lane = tid & 63;
    const int wave = tid >> 6;
    const int lo   = lane & 15;
    const int hi   = lane >> 4;
    const int wr   = wave >> 1;
    const int wc   = wave & 1;
    const int nstart = blockIdx.x * 128;
    const int mstart = blockIdx.y * 128;

    f32x4 acc[4][4];
    #pragma unroll
    for (int i = 0; i < 4; ++i)
        #pragma unroll
        for (int j = 0; j < 4; ++j) acc[i][j] = (f32x4){0.f,0.f,0.f,0.f};

    for (int k0 = 0; k0 < E_; k0 += 64) {
        __syncthreads();
        #pragma unroll
        for (int it = 0; it < 4; ++it) {
            const int cid = tid + it*256;
            const int row = cid >> 3, c = cid & 7;
            bf16x8 av = *(const bf16x8*)(xb + (size_t)(mstart + row)*E_ + k0 + c*8);
            *(bf16x8*)&As[row*64 + ((c ^ (row & 7)) * 8)] = av;
            bf16x8 bv = *(const bf16x8*)(Wt + (size_t)(nstart + row)*E_ + k0 + c*8);
            *(bf16x8*)&Bs[row*64 + ((c ^ (row & 7)) * 8)] = bv;
        }
        __syncthreads();

        #pragma unroll
        for (int ks = 0; ks < 2; ++ks) {
            const int c = ks*4 + hi;
            bf16x8 af[4], bfr[4];
            #pragma unroll
            for (int i = 0; i < 4; ++i) {
                const int ar = wr*64 + i*16 + lo;
                af[i] = *(const bf16x8*)&As[ar*64 + ((c ^ (ar & 7)) * 8)];
            }
            #pragma unroll
            for (int j = 0; j < 4; ++j) {
                const int br = wc*64 + j*16 + lo;
                bfr[j] = *(const bf16x8*)&Bs[br*64 + ((c ^ (br & 7)) * 8)];
            }
            #pragma unroll
            for (int i = 0; i < 4; ++i)
                #pragma unroll
                for (int j = 0; j < 4; ++j)
                    acc[i][j] = __builtin_amdgcn_mfma_f32_16x16x32_bf16(
                        af[i], bfr[j], acc[i][j], 0, 0, 0);
        }
    }

    #pragma unroll
    for (int j = 0; j < 4; ++j) {
        const int ncol = nstart + wc*64 + j*16 + lo;
        const int g  = ncol >> 6;
        const int cq = g / H_;         // 0:Q 1:K 2:V
        const int h  = g % H_;
        const int d  = ncol & 63;
        const float bv = bias[ncol];
        const float qscale = (cq == 0) ? 0.125f : 1.0f;   // fold in 1/sqrt(D)
        unsigned short* dst = qkv + (size_t)cq * QKV_ELEMS;
        #pragma unroll
        for (int i = 0; i < 4; ++i) {
            const int mbase = mstart + wr*64 + i*16 + hi*4;
            const int b  = mbase >> 11;
            const int s0 = mbase & 2047;     // 4-aligned; +3 can't cross 2048
            if (cq == 2) {
                // V transposed: vtg[((b*H+h)*D + d)*S + s], 4 consecutive s
                ushort4 vv;
                vv.x = f2bf(acc[i][j][0] + bv);
                vv.y = f2bf(acc[i][j][1] + bv);
                vv.z = f2bf(acc[i][j][2] + bv);
                vv.w = f2bf(acc[i][j][3] + bv);
                *(ushort4*)(vtg + (((size_t)(b*H_ + h))*D_ + d)*S_ + s0) = vv;
            } else {
                #pragma unroll
                for (int r = 0; r < 4; ++r)
                    dst[(((size_t)(b*H_ + h))*S_ + s0 + r)*D_ + d] =
                        f2bf((acc[i][j][r] + bv) * qscale);
            }
        }
    }
}

// ---------------------------------------------------------------------------
// Flash attention, 32x32x16 bf16 MFMA, swapped operands. Round-15 bisect:
// H1 = the permlane COPY-PAIR (same-value regs -> allocator coalesces ->
// "v_permlane32_swap_b32 v5, v5" row-exchange-in-place -> partner-only max)
// was the round-8/14 bug. So: max/psum use validated __shfl_xor; PV mux uses
// permlane FORM-A (round-8 original, re-derived correct under the
// dst.row1<->src.row0 semantic; X,Y are distinct values -> no coalescing).
// Everything else identical to the round-11 validated kernel.
// ---------------------------------------------------------------------------
__global__ __launch_bounds__(256, 2)
void attn_mfma32(const unsigned short* __restrict__ qkv,
                 const unsigned short* __restrict__ vtg,
                 float* __restrict__ out)
{
    __shared__ __align__(16) unsigned short Ks[2*64*64];  // [buf][key][d], swizzled
    __shared__ __align__(16) unsigned short Vt[2*64*64];  // [buf][d][key], swizzled

    const int tid  = threadIdx.x;
    const int lane = tid & 63;
    const int wave = tid >> 6;       // 0..3
    const int q32  = lane & 31;
    const int hi   = lane >> 5;      // 0..1
    const int qtile = blockIdx.x * 128;
    const int bh = blockIdx.y;
    const size_t base  = (size_t)bh * S_ * D_;
    const size_t baseT = (size_t)bh * D_ * S_;

    const unsigned short* Q = qkv;
    const unsigned short* K = qkv + QKV_ELEMS;

    // Q as B-operand: col=q32, k-elems d = m*16 + hi*8 + j
    bf16x8 qf[4];
    {
        const size_t qrow = base + (size_t)(qtile + wave*32 + q32) * D_;
        #pragma unroll
        for (int m = 0; m < 4; ++m)
            qf[m] = *(const bf16x8*)(Q + qrow + m*16 + hi*8);
    }

    // K staging ids: LDS pos (key=cid>>3, slot=cid&7); source d-chunk = slot^(key&7)
    const int kkey0 = tid >> 3,          kch0 = tid & 7;
    const int kkey1 = (tid + 256) >> 3,  kch1 = (tid + 256) & 7;
    // V^T staging ids: LDS pos (d=cid>>3, slot=cid&7); source key-chunk = slot^(d&7)
    const int vd0 = tid >> 3, vs0 = tid & 7;
    const int vd1 = vd0 + 32;                 // (vd1&7)==(vd0&7)

    #define GLOADK(kc_, buf_) do {                                                   \
        __builtin_amdgcn_global_load_lds(                                            \
            (const __attribute__((address_space(1))) unsigned*)                      \
                (K + base + (size_t)((kc_) + kkey0)*D_ + ((kch0 ^ (kkey0 & 7))*8)),  \
            (__attribute__((address_space(3))) unsigned*)&Ks[(buf_)*4096 + tid*8],   \
            16, 0, 0);                                                               \
        __builtin_amdgcn_global_load_lds(                                            \
            (const __attribute__((address_space(1))) unsigned*)                      \
                (K + base + (size_t)((kc_) + kkey1)*D_ + ((kch1 ^ (kkey1 & 7))*8)),  \
            (__attribute__((address_space(3))) unsigned*)&Ks[(buf_)*4096 + (tid+256)*8], \
            16, 0, 0);                                                               \
    } while (0)
    #define GLOADV(kc_, buf_) do {                                                   \
        __builtin_amdgcn_global_load_lds(                                            \
            (const __attribute__((address_space(1))) unsigned*)                      \
                (vtg + baseT + (size_t)vd0*S_ + (kc_) + ((vs0 ^ (vd0 & 7))*8)),      \
            (__attribute__((address_space(3))) unsigned*)&Vt[(buf_)*4096 + tid*8],   \
            16, 0, 0);                                                               \
        __builtin_amdgcn_global_load_lds(                                            \
            (const __attribute__((address_space(1))) unsigned*)                      \
                (vtg + baseT + (size_t)vd1*S_ + (kc_) + ((vs0 ^ (vd1 & 7))*8)),      \
            (__attribute__((address_space(3))) unsigned*)&Vt[(buf_)*4096 + (tid+256)*8], \
            16, 0, 0);                                                               \
    } while (0)

    f32x16 o0, o1;       // O^T accum: u=0 -> d=0..31, u=1 -> d=32..63 (col=q32)
    #pragma unroll
    for (int r = 0; r < 16; ++r) { o0[r] = 0.f; o1[r] = 0.f; }
    float m_run = -INFINITY, l_run = 0.f;

    // prologue: stage chunk 0
    GLOADK(0, 0);
    GLOADV(0, 0);
    __syncthreads();
    int cur = 0;

    for (int kc = 0; kc < S_; kc += 64) {
        // issue next chunk's DMA now; buf[cur^1] is free (barrier passed)
        const int nkc = (kc + 64 < S_) ? (kc + 64) : 0;
        GLOADK(nkc, cur ^ 1);
        GLOADV(nkc, cur ^ 1);

        const int o = cur * 4096;

        // ---- S^T = K · Q^T : sg[g] covers keys [kc+32g, kc+32g+32)
        f32x16 sg[2];
        __builtin_amdgcn_s_setprio(1);
        #pragma unroll
        for (int g = 0; g < 2; ++g) {
            f32x16 acc;
            #pragma unroll
            for (int r = 0; r < 16; ++r) acc[r] = 0.f;
            const int key = g*32 + q32;
            #pragma unroll
            for (int m = 0; m < 4; ++m) {
                const int c = m*2 + hi;
                bf16x8 kf = *(const bf16x8*)&Ks[o + key*64 + ((c ^ (key & 7)) * 8)];
                acc = __builtin_amdgcn_mfma_f32_32x32x16_bf16(kf, qf[m], acc, 0, 0, 0);
            }
            sg[g] = acc;
        }
        __builtin_amdgcn_s_setprio(0);

        // ---- online softmax, per-lane q = q32; partner = lane^32
        float m0 = fmaxf(sg[0][0], sg[0][1]);
        float m1 = fmaxf(sg[0][8], sg[0][9]);
        float m2 = fmaxf(sg[1][0], sg[1][1]);
        float m3 = fmaxf(sg[1][8], sg[1][9]);
        #pragma unroll
        for (int r = 2; r < 8; r += 2) {
            m0 = max3f(m0, sg[0][r],   sg[0][r+1]);
            m1 = max3f(m1, sg[0][r+8], sg[0][r+9]);
            m2 = max3f(m2, sg[1][r],   sg[1][r+1]);
            m3 = max3f(m3, sg[1][r+8], sg[1][r+9]);
        }
        float mx = fmaxf(fmaxf(m0, m1), fmaxf(m2, m3));
        mx = fmaxf(mx, __shfl_xor(mx, 32));      // validated cross-half max

        // defer-max (T13): only rescale when the max actually grew
        if (__any(mx > m_run + 8.0f)) {
            const float mn    = fmaxf(m_run, mx);
            const float alpha = exp2_fast((m_run - mn) * LOG2E);
            m_run = mn;
            l_run *= alpha;
            #pragma unroll
            for (int r = 0; r < 16; ++r) { o0[r] *= alpha; o1[r] *= alpha; }
        }
        const float nmnL = -m_run * LOG2E;

        // exp via 2^(s*log2e - m*log2e), in place
        #pragma unroll
        for (int r = 0; r < 16; ++r) sg[0][r] = exp2_fast(fmaf(sg[0][r], LOG2E, nmnL));
        #pragma unroll
        for (int r = 0; r < 16; ++r) sg[1][r] = exp2_fast(fmaf(sg[1][r], LOG2E, nmnL));

        // pairwise psum tree + validated cross-half add
        float a8[8];
        #pragma unroll
        for (int r = 0; r < 8; ++r) a8[r] = (sg[0][r] + sg[0][r+8]) + (sg[1][r] + sg[1][r+8]);
        float a4_0 = a8[0] + a8[4], a4_1 = a8[1] + a8[5];
        float a4_2 = a8[2] + a8[6], a4_3 = a8[3] + a8[7];
        float psum = (a4_0 + a4_1) + (a4_2 + a4_3);
        psum += __shfl_xor(psum, 32);
        l_run += psum;

        // ---- pack P to bf16 pairs: U[g][c] = pk(p[2c], p[2c+1])
        unsigned U0[8], U1[8];
        #pragma unroll
        for (int c2 = 0; c2 < 8; ++c2) {
            asm("v_cvt_pk_bf16_f32 %0, %1, %2"
                : "=v"(U0[c2]) : "v"(sg[0][2*c2]), "v"(sg[0][2*c2+1]));
            asm("v_cvt_pk_bf16_f32 %0, %1, %2"
                : "=v"(U1[c2]) : "v"(sg[1][2*c2]), "v"(sg[1][2*c2+1]));
        }

        // ---- PV: O^T += V^T · P^T. B-operand via permlane32_swap FORM-A:
        // A=U[4tb+w'], B=U[4tb+2+w']; swap(dst=A, src=B). Semantic
        // dst.row1<->src.row0 gives: A' = [own-lo | partner-lo-of-B... ] i.e.
        //   row0 lane: A'=own U[4tb+w'],    B'=partner U[4tb+w']
        //   row1 lane: A'=partner U[4tb+2+w'], B'=own U[4tb+2+w']
        // -> pw.w[w']=A', pw.w[2+w']=B'  == validated shfl mux, both halves.
        __builtin_amdgcn_s_setprio(1);
        #pragma unroll
        for (int t = 0; t < 4; ++t) {
            const int tb = t & 1;
            unsigned* Ug = (t < 2) ? U0 : U1;
            union { unsigned w[4]; bf16x8 v; } pw;
            #pragma unroll
            for (int w2 = 0; w2 < 2; ++w2) {
                unsigned A  = Ug[4*tb + w2];
                unsigned Bv = Ug[4*tb + 2 + w2];
                asm("v_permlane32_swap_b32 %0, %1" : "+v"(A), "+v"(Bv));
                pw.w[w2]     = A;
                pw.w[2 + w2] = Bv;
            }
            const int c = t*2 + hi;
            {
                const int d = q32;
                bf16x8 vf = *(const bf16x8*)&Vt[o + d*64 + ((c ^ (d & 7)) * 8)];
                o0 = __builtin_amdgcn_mfma_f32_32x32x16_bf16(vf, pw.v, o0, 0, 0, 0);
            }
            {
                const int d = 32 + q32;
                bf16x8 vf = *(const bf16x8*)&Vt[o + d*64 + ((c ^ (d & 7)) * 8)];
                o1 = __builtin_amdgcn_mfma_f32_32x32x16_bf16(vf, pw.v, o1, 0, 0, 0);
            }
        }
        __builtin_amdgcn_s_setprio(0);

        // ---- single barrier per chunk: drains next-chunk DMA + gates reuse
        __syncthreads();
        cur ^= 1;
    }

    // ---- epilogue: O^T[d][q], lane writes row q = qtile+wave*32+q32
    const int b = bh / H_;
    const int h = bh % H_;
    const float inv = 1.f / l_run;
    const int qglob = qtile + wave*32 + q32;
    float* obase = out + ((size_t)b*S_ + qglob)*E_ + h*64;
    #pragma unroll
    for (int rg = 0; rg < 4; ++rg) {
        float4 w0 = { o0[4*rg+0]*inv, o0[4*rg+1]*inv, o0[4*rg+2]*inv, o0[4*rg+3]*inv };
        *(float4*)(obase + rg*8 + hi*4) = w0;
        float4 w1 = { o1[4*rg+0]*inv, o1[4*rg+1]*inv, o1[4*rg+2]*inv, o1[4*rg+3]*inv };
        *(float4*)(obase + 32 + rg*8 + hi*4) = w1;
    }
    #undef GLOADK
    #undef GLOADV
}

// ---------------------------------------------------------------------------
extern "C" void kernel_launch(void* const* d_in, const int* in_sizes, int n_in,
                              void* d_out, int out_size, void* d_ws, size_t ws_size,
                              hipStream_t stream)
{
    (void)in_sizes; (void)n_in; (void)out_size; (void)ws_size;
    const float* x    = (const float*)d_in[0];
    const float* W    = (const float*)d_in[1];
    const float* bias = (const float*)d_in[2];
    float* out = (float*)d_out;

    unsigned short* qkv = (unsigned short*)d_ws;            // Q,K,(V unused) 37.7 MB
    unsigned short* xb  = qkv + 3*QKV_ELEMS;                // 12.6 MB
    unsigned short* Wtb = xb + (size_t)B_*S_*E_;            // 3.5 MB
    unsigned short* vtg = Wtb + (size_t)E_*NE3;             // V^T [B,H,D,S] 12.6 MB

    cvt_x<<<(B_*S_*E_)/(256*8), 256, 0, stream>>>(x, xb);
    transpose_w<<<dim3(NE3/32, E_/32), 256, 0, stream>>>(W, Wtb);

    dim3 g1(NE3/128, (B_*S_)/128);   // (18, 64)
    qkv_gemm_mfma<<<g1, 256, 0, stream>>>(xb, Wtb, bias, qkv, vtg);

    dim3 g2(S_/128, B_*H_);          // (16, 48)
    attn_mfma32<<<g2, 256, 0, stream>>>(qkv, vtg, out);
}